// Round 16
// baseline (136.883 us; speedup 1.0000x reference)
//
#include <hip/hip_runtime.h>

#define NCLS 88
#define DHW (96 * 96 * 96)            // 884736
#define TPB 256                       // 4 waves, 4-way class split
#define WAVES 4
#define CPW 22                        // classes per wave
#define VOX_PER_BLOCK 256             // 4 voxels per lane, one float4 group
#define BLOCKS_PER_B (DHW / VOX_PER_BLOCK)   // 3456, exact
#define SLOTS 32
#define SMOOTH 1e-5f
#define WS_PER_SLOT 529
// ws layout per slot: [0..176) inter[b*88+c] | [176..352) pred_o | [352..528) cnt | [528] ce

typedef float f2 __attribute__((ext_vector_type(2)));
typedef float f4 __attribute__((ext_vector_type(4)));
typedef int   i4 __attribute__((ext_vector_type(4)));
typedef __fp16 h2 __attribute__((ext_vector_type(2)));
union H2I { h2 h; int i; };
union FI  { float f; int i; };

// ---- DPP wave-64 sum: pure VALU (no DS pipe). After the 6 steps lane 63
// holds the full-wave sum. row_shr:N = 0x110|N, row_bcast15=0x142 (rows 1,3),
// row_bcast31=0x143 (rows 2,3). old=0 + masked rows -> contribute 0.
#define DPP_STEP_I(acc_i, ctrl, rmask)                                          \
    __builtin_amdgcn_update_dpp(0, (acc_i), (ctrl), (rmask), 0xf, true)

__device__ __forceinline__ float dpp_wave_sum_f32(float v) {
    FI a; a.f = v; FI t;
    t.i = DPP_STEP_I(a.i, 0x111, 0xf); a.f += t.f;
    t.i = DPP_STEP_I(a.i, 0x112, 0xf); a.f += t.f;
    t.i = DPP_STEP_I(a.i, 0x114, 0xf); a.f += t.f;
    t.i = DPP_STEP_I(a.i, 0x118, 0xf); a.f += t.f;
    t.i = DPP_STEP_I(a.i, 0x142, 0xa); a.f += t.f;
    t.i = DPP_STEP_I(a.i, 0x143, 0xc); a.f += t.f;
    return a.f;                        // valid in lane 63
}

__device__ __forceinline__ h2 dpp_wave_sum_h2(h2 v) {
    H2I a; a.h = v; H2I t;
    t.i = DPP_STEP_I(a.i, 0x111, 0xf); a.h = a.h + t.h;   // v_pk_add_f16
    t.i = DPP_STEP_I(a.i, 0x112, 0xf); a.h = a.h + t.h;
    t.i = DPP_STEP_I(a.i, 0x114, 0xf); a.h = a.h + t.h;
    t.i = DPP_STEP_I(a.i, 0x118, 0xf); a.h = a.h + t.h;
    t.i = DPP_STEP_I(a.i, 0x142, 0xa); a.h = a.h + t.h;
    t.i = DPP_STEP_I(a.i, 0x143, 0xc); a.h = a.h + t.h;
    return a.h;                        // valid in lane 63
}

__device__ __forceinline__ float wave_reduce_sum(float v) {
#pragma unroll
    for (int i = 1; i < 64; i <<= 1)
        v += __shfl_xor(v, i, 64);
    return v;
}

// NOTE: no min-waves arg — __launch_bounds__(TPB,N) forced 64-VGPR + ~1.5 GB
// spill traffic in R4/R6. R15 structure (117.7 µs) with the pass-B and CE
// reductions moved off the DS pipe (DPP) and pred_o written straight to the
// striped global slot by lane 63 (deletes s_pred + 44 LDS RMWs/wave).
__global__ __launch_bounds__(TPB)
void seg_loss_main(const float* __restrict__ pred, const int* __restrict__ tgt,
                   float* __restrict__ ws) {
    __shared__ float s_inter[NCLS];
    __shared__ float s_cnt[NCLS];
    __shared__ float2 s_ex[WAVES][4][64];  // [wave][vox][lane] = {s1_part, et_part}, 8 KB

    const int tid  = threadIdx.x;
    const int lane = tid & 63;
    const int wave = tid >> 6;                 // 0..3
    const int b    = blockIdx.x / BLOCKS_PER_B;
    const int base = (blockIdx.x % BLOCKS_PER_B) * VOX_PER_BLOCK;
    const int cls0 = wave * CPW;
    const float* pb = pred + (size_t)b * NCLS * DHW + (size_t)cls0 * DHW;
    const int*   tb = tgt  + (size_t)b * DHW;
    float* wsl = ws + (size_t)(blockIdx.x & (SLOTS - 1)) * WS_PER_SLOT;

    // ---- targets: 4 voxels per lane, coalesced int4, non-temporal ----
    const i4 t4 = __builtin_nontemporal_load((const i4*)(tb + base + lane * 4));
    const int tv[4] = { t4.x, t4.y, t4.z, t4.w };
    bool val[4]; int tc[4]; float vf[4];
#pragma unroll
    for (int v = 0; v < 4; ++v) {
        val[v] = (tv[v] != -1);
        tc[v]  = val[v] ? tv[v] : 0;
        vf[v]  = val[v] ? 1.f : 0.f;
    }

    // ---- pass A: 22 classes x float4 (4 voxels/lane), nt loads, fp8-packed exps ----
    const float* p = pb + base + lane * 4;
    float s[4]  = {0, 0, 0, 0};
    float et[4] = {0, 0, 0, 0};
    int ef[CPW];
#pragma unroll
    for (int c = 0; c < CPW; ++c) {
        const f4 x = __builtin_nontemporal_load((const f4*)(p + (size_t)c * DHW));
        const float e0 = __expf(x.x * vf[0]);
        const float e1 = __expf(x.y * vf[1]);
        const float e2 = __expf(x.z * vf[2]);
        const float e3 = __expf(x.w * vf[3]);
        s[0] += e0; s[1] += e1; s[2] += e2; s[3] += e3;
        const int cc = cls0 + c;
        et[0] = (cc == tc[0]) ? e0 : et[0];
        et[1] = (cc == tc[1]) ? e1 : et[1];
        et[2] = (cc == tc[2]) ? e2 : et[2];
        et[3] = (cc == tc[3]) ? e3 : et[3];
        const int lo = __builtin_amdgcn_cvt_pk_fp8_f32(e0, e1, 0, false);
        ef[c] = __builtin_amdgcn_cvt_pk_fp8_f32(e2, e3, lo, true);
    }

    // ---- LDS init folded before the single exchange barrier ----
    if (tid < NCLS) { s_inter[tid] = 0.f; s_cnt[tid] = 0.f; }
#pragma unroll
    for (int v = 0; v < 4; ++v)
        s_ex[wave][v][lane] = make_float2(s[v], et[v]);
    __syncthreads();

    float inv[4], pt[4];
#pragma unroll
    for (int v = 0; v < 4; ++v) {
        const float2 q0 = s_ex[0][v][lane];
        const float2 q1 = s_ex[1][v][lane];
        const float2 q2 = s_ex[2][v][lane];
        const float2 q3 = s_ex[3][v][lane];
        const float s1 = (q0.x + q1.x) + (q2.x + q3.x);
        const float e  = (q0.y + q1.y) + (q2.y + q3.y);
        inv[v] = 1.f / s1;
        pt[v]  = e * inv[v];
    }

    // ---- CE + inter/cnt, owner wave only ----
    float ce_acc = 0.f;
#pragma unroll
    for (int v = 0; v < 4; ++v) {
        const bool own = (tc[v] >= cls0) && (tc[v] < cls0 + CPW);
        if (val[v] && own) {
            ce_acc -= __logf(pt[v]);
            atomicAdd(&s_inter[tc[v]], pt[v]);
            atomicAdd(&s_cnt[tc[v]], 1.f);
        }
    }

    // ---- pass B: p^2 per class over 4 voxels; DPP reduce (VALU-only),
    //      lane 63 writes pred_o straight to the striped global slot ----
#pragma unroll
    for (int q = 0; q < CPW / 2; ++q) {
        const f2 lo0 = __builtin_amdgcn_cvt_pk_f32_fp8(ef[2 * q],     false);
        const f2 hi0 = __builtin_amdgcn_cvt_pk_f32_fp8(ef[2 * q],     true);
        const f2 lo1 = __builtin_amdgcn_cvt_pk_f32_fp8(ef[2 * q + 1], false);
        const f2 hi1 = __builtin_amdgcn_cvt_pk_f32_fp8(ef[2 * q + 1], true);
        const float a0 = lo0.x * inv[0], a1 = lo0.y * inv[1];
        const float a2 = hi0.x * inv[2], a3 = hi0.y * inv[3];
        const float b0 = lo1.x * inv[0], b1 = lo1.y * inv[1];
        const float b2 = hi1.x * inv[2], b3 = hi1.y * inv[3];
        const float sq0 = (a0 * a0 + a1 * a1) + (a2 * a2 + a3 * a3);
        const float sq1 = (b0 * b0 + b1 * b1) + (b2 * b2 + b3 * b3);
        const h2 r = dpp_wave_sum_h2(__builtin_amdgcn_cvt_pkrtz(sq0, sq1));
        if (lane == 63) {
            atomicAdd(&wsl[176 + b * NCLS + cls0 + 2 * q],     (float)r.x);
            atomicAdd(&wsl[176 + b * NCLS + cls0 + 2 * q + 1], (float)r.y);
        }
    }
    const float ce_w = dpp_wave_sum_f32(ce_acc);
    if (lane == 63) atomicAdd(&wsl[528], ce_w);

    __syncthreads();

    // ---- block partials (inter/cnt only) -> striped global slots ----
    if (tid < NCLS) {
        atomicAdd(&wsl[0 * 176 + b * NCLS + tid], s_inter[tid]);
        atomicAdd(&wsl[2 * 176 + b * NCLS + tid], s_cnt[tid]);
    }
}

__global__ __launch_bounds__(256)
void seg_loss_final(const float* __restrict__ ws, float* __restrict__ out) {
    const int tid = threadIdx.x;
    float dice = 0.f, cnt = 0.f;
    if (tid < 2 * NCLS) {
        float I = 0.f, P = 0.f, G = 0.f;
        for (int s = 0; s < SLOTS; ++s) {
            const float* w = ws + (size_t)s * WS_PER_SLOT;
            I += w[tid]; P += w[176 + tid]; G += w[352 + tid];
        }
        dice = 1.f - (2.f * I + SMOOTH) / (G + P + SMOOTH);
        cnt  = G;
    }
    float ce_s = 0.f;
    if (tid < SLOTS) ce_s = ws[(size_t)tid * WS_PER_SLOT + 528];

    dice = wave_reduce_sum(dice);
    cnt  = wave_reduce_sum(cnt);
    ce_s = wave_reduce_sum(ce_s);

    __shared__ float sd[4], sc2[4], se[4];
    const int w = tid >> 6, l = tid & 63;
    if (l == 0) { sd[w] = dice; sc2[w] = cnt; se[w] = ce_s; }
    __syncthreads();
    if (tid == 0) {
        const float D  = sd[0] + sd[1] + sd[2] + sd[3];
        const float Cn = sc2[0] + sc2[1] + sc2[2] + sc2[3];
        const float CE = (se[0] + se[1] + se[2] + se[3]) / fmaxf(Cn, 1.0f);
        out[0] = 0.4f * CE + 0.6f * (D / 176.f);
    }
}

extern "C" void kernel_launch(void* const* d_in, const int* in_sizes, int n_in,
                              void* d_out, int out_size, void* d_ws, size_t ws_size,
                              hipStream_t stream) {
    const float* pred = (const float*)d_in[0];
    const int*   tgt  = (const int*)d_in[1];
    float* ws = (float*)d_ws;

    (void)hipMemsetAsync(d_ws, 0, SLOTS * WS_PER_SLOT * sizeof(float), stream);
    seg_loss_main<<<2 * BLOCKS_PER_B, TPB, 0, stream>>>(pred, tgt, ws);
    seg_loss_final<<<1, 256, 0, stream>>>(ws, (float*)d_out);
}

// Round 17
// 117.223 us; speedup vs baseline: 1.1677x; 1.1677x over previous
//
#include <hip/hip_runtime.h>

#define NCLS 88
#define DHW (96 * 96 * 96)            // 884736
#define TPB 256                       // 4 waves, 4-way class split
#define WAVES 4
#define CPW 22                        // classes per wave
#define VOX_PER_BLOCK 256             // 4 voxels per lane, one float4 group
#define BLOCKS_PER_B (DHW / VOX_PER_BLOCK)   // 3456, exact
#define SLOTS 32
#define SMOOTH 1e-5f
#define WS_PER_SLOT 529
// ws layout per slot: [0..176) inter[b*88+c] | [176..352) pred_o | [352..528) cnt | [528] ce

typedef float f2 __attribute__((ext_vector_type(2)));
typedef float f4 __attribute__((ext_vector_type(4)));
typedef int   i4 __attribute__((ext_vector_type(4)));
typedef __fp16 h2 __attribute__((ext_vector_type(2)));
union H2I { h2 h; int i; };

__device__ __forceinline__ float wave_reduce_sum(float v) {
#pragma unroll
    for (int i = 1; i < 64; i <<= 1)
        v += __shfl_xor(v, i, 64);
    return v;
}

__device__ __forceinline__ h2 wave_reduce_h2(h2 v) {
#pragma unroll
    for (int i = 1; i < 64; i <<= 1) {
        H2I u; u.h = v;
        u.i = __shfl_xor(u.i, i, 64);
        v = v + u.h;                   // v_pk_add_f16
    }
    return v;
}

// NOTE: no min-waves arg — __launch_bounds__(TPB,N) forced 64-VGPR + ~1.5 GB
// spill traffic in R4/R6. R15 structure (117.7 µs) with the tail shortened:
// s_pred plain-store (sole owner), second barrier removed (per-wave writeback
// of own class range), CE straight to global (1 atomic/wave).
__global__ __launch_bounds__(TPB)
void seg_loss_main(const float* __restrict__ pred, const int* __restrict__ tgt,
                   float* __restrict__ ws) {
    __shared__ float s_inter[NCLS];
    __shared__ float s_pred[NCLS];
    __shared__ float s_cnt[NCLS];
    __shared__ float2 s_ex[WAVES][4][64];  // [wave][vox][lane] = {s1_part, et_part}, 8 KB

    const int tid  = threadIdx.x;
    const int lane = tid & 63;
    const int wave = tid >> 6;                 // 0..3
    const int b    = blockIdx.x / BLOCKS_PER_B;
    const int base = (blockIdx.x % BLOCKS_PER_B) * VOX_PER_BLOCK;
    const int cls0 = wave * CPW;
    const float* pb = pred + (size_t)b * NCLS * DHW + (size_t)cls0 * DHW;
    const int*   tb = tgt  + (size_t)b * DHW;
    float* wsl = ws + (size_t)(blockIdx.x & (SLOTS - 1)) * WS_PER_SLOT;

    // ---- targets: 4 voxels per lane, coalesced int4, non-temporal ----
    const i4 t4 = __builtin_nontemporal_load((const i4*)(tb + base + lane * 4));
    const int tv[4] = { t4.x, t4.y, t4.z, t4.w };
    bool val[4]; int tc[4]; float vf[4];
#pragma unroll
    for (int v = 0; v < 4; ++v) {
        val[v] = (tv[v] != -1);
        tc[v]  = val[v] ? tv[v] : 0;
        vf[v]  = val[v] ? 1.f : 0.f;
    }

    // ---- pass A: 22 classes x float4 (4 voxels/lane), nt loads, fp8-packed exps ----
    const float* p = pb + base + lane * 4;
    float s[4]  = {0, 0, 0, 0};
    float et[4] = {0, 0, 0, 0};
    int ef[CPW];
#pragma unroll
    for (int c = 0; c < CPW; ++c) {
        const f4 x = __builtin_nontemporal_load((const f4*)(p + (size_t)c * DHW));
        const float e0 = __expf(x.x * vf[0]);
        const float e1 = __expf(x.y * vf[1]);
        const float e2 = __expf(x.z * vf[2]);
        const float e3 = __expf(x.w * vf[3]);
        s[0] += e0; s[1] += e1; s[2] += e2; s[3] += e3;
        const int cc = cls0 + c;
        et[0] = (cc == tc[0]) ? e0 : et[0];
        et[1] = (cc == tc[1]) ? e1 : et[1];
        et[2] = (cc == tc[2]) ? e2 : et[2];
        et[3] = (cc == tc[3]) ? e3 : et[3];
        const int lo = __builtin_amdgcn_cvt_pk_fp8_f32(e0, e1, 0, false);
        ef[c] = __builtin_amdgcn_cvt_pk_fp8_f32(e2, e3, lo, true);
    }

    // ---- LDS init folded before the single exchange barrier ----
    if (tid < NCLS) { s_inter[tid] = 0.f; s_cnt[tid] = 0.f; }
#pragma unroll
    for (int v = 0; v < 4; ++v)
        s_ex[wave][v][lane] = make_float2(s[v], et[v]);
    __syncthreads();

    float inv[4], pt[4];
#pragma unroll
    for (int v = 0; v < 4; ++v) {
        const float2 q0 = s_ex[0][v][lane];
        const float2 q1 = s_ex[1][v][lane];
        const float2 q2 = s_ex[2][v][lane];
        const float2 q3 = s_ex[3][v][lane];
        const float s1 = (q0.x + q1.x) + (q2.x + q3.x);
        const float e  = (q0.y + q1.y) + (q2.y + q3.y);
        inv[v] = 1.f / s1;
        pt[v]  = e * inv[v];
    }

    // ---- CE + inter/cnt, owner wave only (writes ONLY its own class range) ----
    float ce_acc = 0.f;
#pragma unroll
    for (int v = 0; v < 4; ++v) {
        const bool own = (tc[v] >= cls0) && (tc[v] < cls0 + CPW);
        if (val[v] && own) {
            ce_acc -= __logf(pt[v]);
            atomicAdd(&s_inter[tc[v]], pt[v]);
            atomicAdd(&s_cnt[tc[v]], 1.f);
        }
    }

    // ---- pass B: p^2 per class; h2 butterfly; lane 0 plain-stores (sole owner) ----
#pragma unroll
    for (int q = 0; q < CPW / 2; ++q) {
        const f2 lo0 = __builtin_amdgcn_cvt_pk_f32_fp8(ef[2 * q],     false);
        const f2 hi0 = __builtin_amdgcn_cvt_pk_f32_fp8(ef[2 * q],     true);
        const f2 lo1 = __builtin_amdgcn_cvt_pk_f32_fp8(ef[2 * q + 1], false);
        const f2 hi1 = __builtin_amdgcn_cvt_pk_f32_fp8(ef[2 * q + 1], true);
        const float a0 = lo0.x * inv[0], a1 = lo0.y * inv[1];
        const float a2 = hi0.x * inv[2], a3 = hi0.y * inv[3];
        const float b0 = lo1.x * inv[0], b1 = lo1.y * inv[1];
        const float b2 = hi1.x * inv[2], b3 = hi1.y * inv[3];
        const float sq0 = (a0 * a0 + a1 * a1) + (a2 * a2 + a3 * a3);
        const float sq1 = (b0 * b0 + b1 * b1) + (b2 * b2 + b3 * b3);
        h2 r = wave_reduce_h2(__builtin_amdgcn_cvt_pkrtz(sq0, sq1));
        if (lane == 0) {
            s_pred[cls0 + 2 * q]     = (float)r.x;   // sole owner -> plain store
            s_pred[cls0 + 2 * q + 1] = (float)r.y;
        }
    }

    // ---- per-wave writeback of OWN class range; no second barrier.
    //      In-wave LDS ordering (lgkmcnt) makes this wave's scatter/stores
    //      visible to its own reads; no cross-wave data flows here. ----
    if (lane < CPW) {
        const int c = cls0 + lane;
        atomicAdd(&wsl[0 * 176 + b * NCLS + c], s_inter[c]);
        atomicAdd(&wsl[176     + b * NCLS + c], s_pred[c]);
        atomicAdd(&wsl[352     + b * NCLS + c], s_cnt[c]);
    }
    const float ce_w = wave_reduce_sum(ce_acc);
    if (lane == 0) atomicAdd(&wsl[528], ce_w);
}

__global__ __launch_bounds__(256)
void seg_loss_final(const float* __restrict__ ws, float* __restrict__ out) {
    const int tid = threadIdx.x;
    float dice = 0.f, cnt = 0.f;
    if (tid < 2 * NCLS) {
        float I = 0.f, P = 0.f, G = 0.f;
        for (int s = 0; s < SLOTS; ++s) {
            const float* w = ws + (size_t)s * WS_PER_SLOT;
            I += w[tid]; P += w[176 + tid]; G += w[352 + tid];
        }
        dice = 1.f - (2.f * I + SMOOTH) / (G + P + SMOOTH);
        cnt  = G;
    }
    float ce_s = 0.f;
    if (tid < SLOTS) ce_s = ws[(size_t)tid * WS_PER_SLOT + 528];

    dice = wave_reduce_sum(dice);
    cnt  = wave_reduce_sum(cnt);
    ce_s = wave_reduce_sum(ce_s);

    __shared__ float sd[4], sc2[4], se[4];
    const int w = tid >> 6, l = tid & 63;
    if (l == 0) { sd[w] = dice; sc2[w] = cnt; se[w] = ce_s; }
    __syncthreads();
    if (tid == 0) {
        const float D  = sd[0] + sd[1] + sd[2] + sd[3];
        const float Cn = sc2[0] + sc2[1] + sc2[2] + sc2[3];
        const float CE = (se[0] + se[1] + se[2] + se[3]) / fmaxf(Cn, 1.0f);
        out[0] = 0.4f * CE + 0.6f * (D / 176.f);
    }
}

extern "C" void kernel_launch(void* const* d_in, const int* in_sizes, int n_in,
                              void* d_out, int out_size, void* d_ws, size_t ws_size,
                              hipStream_t stream) {
    const float* pred = (const float*)d_in[0];
    const int*   tgt  = (const int*)d_in[1];
    float* ws = (float*)d_ws;

    (void)hipMemsetAsync(d_ws, 0, SLOTS * WS_PER_SLOT * sizeof(float), stream);
    seg_loss_main<<<2 * BLOCKS_PER_B, TPB, 0, stream>>>(pred, tgt, ws);
    seg_loss_final<<<1, 256, 0, stream>>>(ws, (float*)d_out);
}